// Round 15
// baseline (457.876 us; speedup 1.0000x reference)
//
#include <hip/hip_runtime.h>

namespace {

constexpr int B_N = 8;
constexpr int A_N = 100000;
constexpr int M_N = 128;
constexpr int BLOCK = 256;
constexpr int NBLK_S = (A_N + BLOCK - 1) / BLOCK;  // 391
constexpr int GX = 16, GY = 9, NC = GX * GY;       // 144 cells, 120x120
constexpr float CELL = 120.0f;
constexpr float MARGIN = 128.0f;                   // max anchor half-extent
constexpr int CPC = 4;                             // chunks/cell
constexpr int NCH = NC * CPC;                      // 576 chunk-slots per image
constexpr int NU1 = NBLK_S + B_N * NC;             // 1543 K1 blocks
constexpr unsigned TOTAL4 = (unsigned)(NCH * B_N); // 4608 K3 blocks

// workspace layout (bytes)
constexpr size_t OFF_HIST = 0;                                      // NBLK_S*NC u32
constexpr size_t OFF_CB   = OFF_HIST + (size_t)NBLK_S * NC * 4;     // (NC+1) u32
constexpr size_t OFF_SIDX = (OFF_CB + (NC + 1) * 4 + 15) & ~size_t(15);       // A_N u32
constexpr size_t OFF_SANC = (OFF_SIDX + (size_t)A_N * 4 + 15) & ~size_t(15);  // A_N float4
constexpr size_t OFF_SNEG = OFF_SANC + (size_t)A_N * 16;            // B*A_N f32
constexpr size_t OFF_BL   = OFF_SNEG + (size_t)B_N * A_N * 4;       // B*NC*128*8 f32
constexpr size_t OFF_KL   = OFF_BL + (size_t)B_N * NC * M_N * 8 * 4;  // B*NC u32
constexpr size_t OFF_PART = (OFF_KL + (size_t)B_N * NC * 4 + 15) & ~size_t(15);  // B*NCH*4 f32
constexpr size_t OFF_DONE = OFF_PART + (size_t)B_N * NCH * 4 * 4;   // 1 u32

__device__ __forceinline__ int cell_of(const float4& an) {
    const float acx = 0.5f * (an.x + an.z);
    const float acy = 0.5f * (an.y + an.w);
    const int cx = min(GX - 1, max(0, (int)(acx * (1.0f / CELL))));
    const int cy = min(GY - 1, max(0, (int)(acy * (1.0f / CELL))));
    return cy * GX + cx;
}

// ---------------------------------------------------------------------------
// K1 (validated R12 s1kx): heterogeneous blocks.
//  [0, NBLK_S):      hist + sneg (coalesced cls stream)
//  [NBLK_S, +B*NC):  per-(image,cell) dense box lists {x1,y1,x2,y2,-area,id}
// ---------------------------------------------------------------------------
__global__ __launch_bounds__(BLOCK) void k1_prep(
    const float* __restrict__ anchors_,
    const float* __restrict__ cls_,
    const float* __restrict__ ann_,
    unsigned* __restrict__ hist,     // (NBLK_S, NC)
    float* __restrict__ sneg_,       // (B_N, A_N)
    float* __restrict__ bl,          // (B_N, NC, 128, 8)
    unsigned* __restrict__ kl)       // (B_N, NC)
{
    __shared__ unsigned h[NC];
    __shared__ unsigned long long s_w[2];
    const int blk = blockIdx.x, tid = threadIdx.x;

    if (blk < NBLK_S) {
        for (int i = tid; i < NC; i += BLOCK) h[i] = 0u;
        __syncthreads();
        const int a = blk * BLOCK + tid;
        if (a < A_N) {
            const float4 an = ((const float4*)anchors_)[a];
            atomicAdd(&h[cell_of(an)], 1u);
#pragma unroll
            for (int b = 0; b < B_N; ++b) {
                const float* cp = cls_ + ((size_t)b * A_N + a) * 8;
                const float4 cA = ((const float4*)cp)[0];
                const float4 cB = ((const float4*)cp)[1];
                const float pv[8] = {cA.x, cA.y, cA.z, cA.w, cB.x, cB.y, cB.z, cB.w};
                float s = 0.f;
#pragma unroll
                for (int c = 0; c < 8; ++c) {
                    const float p = fminf(fmaxf(pv[c], 1e-4f), 1.0f - 1e-4f);
                    s += 0.75f * p * p * (-__logf(1.0f - p));
                }
                sneg_[(size_t)b * A_N + a] = s;
            }
        }
        __syncthreads();
        for (int i = tid; i < NC; i += BLOCK) hist[(size_t)blk * NC + i] = h[i];
        return;
    }

    const int bi = blk - NBLK_S;
    const int b  = bi / NC, cc = bi % NC;
    const int ccx = cc % GX, ccy = cc / GX;
    const float lox = ccx * CELL - MARGIN, hix = ccx * CELL + CELL + MARGIN;
    const float loy = ccy * CELL - MARGIN, hiy = ccy * CELL + CELL + MARGIN;
    bool ok = false;
    float minx = 0.f, miny = 0.f, maxx = 0.f, maxy = 0.f, area = 0.f;
    if (tid < M_N) {
        const float* t = ann_ + ((size_t)b * M_N + tid) * 18;
        minx = t[0]; maxx = t[0]; miny = t[1]; maxy = t[1];
#pragma unroll
        for (int j = 1; j < 8; ++j) {
            const float x = t[2 * j], y = t[2 * j + 1];
            minx = fminf(minx, x); maxx = fmaxf(maxx, x);
            miny = fminf(miny, y); maxy = fmaxf(maxy, y);
        }
        area = (maxx - minx) * (maxy - miny);
        ok = (t[17] >= 0.0f) && (minx <= hix) && (maxx >= lox) &&
             (miny <= hiy) && (maxy >= loy);
    }
    const unsigned long long bw = __ballot(ok);
    if (tid < 128 && (tid & 63) == 0) s_w[tid >> 6] = bw;
    __syncthreads();
    const unsigned p0 = (unsigned)__popcll(s_w[0]);
    if (ok) {
        const int wq = tid >> 6;  // 0 or 1
        const int r = (int)((wq ? p0 : 0u) +
            (unsigned)__popcll(s_w[wq] & ((1ull << (tid & 63)) - 1ull)));
        float* o = bl + (((size_t)b * NC + cc) * M_N + r) * 8;
        o[0] = minx; o[1] = miny; o[2] = maxx; o[3] = maxy;
        o[4] = -area; o[5] = (float)tid; o[6] = 0.f; o[7] = 0.f;
    }
    if (tid == 0)
        kl[(size_t)b * NC + cc] = p0 + (unsigned)__popcll(s_w[1]);
}

// ---------------------------------------------------------------------------
// K2 (NEW, merges s2a+s3): each block streams ALL hist rows with coalesced
// loads + LDS integer atomics (deterministic) to build offA[c] (rows < blk)
// and offB[c] (all rows = cell totals); LDS scan -> cell bases; then the
// validated R9 scatter body. Block 0 publishes cellBase and resets `done`.
// ---------------------------------------------------------------------------
__global__ __launch_bounds__(BLOCK) void k2_scan_scatter(
    const float* __restrict__ anchors_,
    const unsigned* __restrict__ hist,   // (NBLK_S, NC)
    unsigned* __restrict__ cellBase,     // NC+1
    unsigned* __restrict__ sidx, float4* __restrict__ sanc,
    unsigned* __restrict__ done)
{
    __shared__ unsigned offA[NC];   // sum of rows < blk  (== offs[c][blk])
    __shared__ unsigned offB[NC];   // sum of all rows    (== cellTot[c])
    __shared__ unsigned sscan[BLOCK];
    __shared__ unsigned scb[NC];
    __shared__ unsigned hw[4][NC];
    const int blk = blockIdx.x, tid = threadIdx.x;
    const int ln = tid & 63, wv = tid >> 6;

    for (int i = tid; i < NC; i += BLOCK) { offA[i] = 0u; offB[i] = 0u; }
    for (int i = tid; i < 4 * NC; i += BLOCK) (&hw[0][0])[i] = 0u;
    if (blk == 0 && tid == 0) *done = 0u;   // reset finisher counter for K3
    __syncthreads();

    for (int idx = tid; idx < NBLK_S * NC; idx += BLOCK) {  // coalesced
        const unsigned v = hist[idx];
        if (v) {
            const int r = idx / NC, c = idx - r * NC;
            atomicAdd(&offB[c], v);               // integer: deterministic
            if (r < blk) atomicAdd(&offA[c], v);
        }
    }
    __syncthreads();

    const unsigned v = (tid < NC) ? offB[tid] : 0u;
    sscan[tid] = v;
    __syncthreads();
    for (int off = 1; off < BLOCK; off <<= 1) {
        const unsigned x = (tid >= off) ? sscan[tid - off] : 0u;
        __syncthreads();
        sscan[tid] += x;
        __syncthreads();
    }
    if (tid < NC) scb[tid] = sscan[tid] - v;
    if (blk == 0) {
        if (tid < NC) cellBase[tid] = sscan[tid] - v;
        if (tid == NC - 1) cellBase[NC] = sscan[tid];
    }

    // scatter (validated R9 body; offs -> offA)
    const int a = blk * BLOCK + tid;
    const bool valid = (a < A_N);
    float4 an = make_float4(0.f, 0.f, 0.f, 0.f);
    int c = -1;
    if (valid) { an = ((const float4*)anchors_)[a]; c = cell_of(an); }

    int rank = 0, cnt = 0;
    for (int j = 0; j < 64; ++j) {           // deterministic intra-wave rank
        const int cj = __shfl(c, j);
        const bool same = (cj == c);
        rank += (same && (j < ln));
        cnt  += same;
    }
    if (valid && rank == 0) hw[wv][c] = (unsigned)cnt;
    __syncthreads();
    if (valid) {
        unsigned r = (unsigned)rank;
        for (int w = 0; w < wv; ++w) r += hw[w][c];
        const unsigned d = scb[c] + offA[c] + r;
        sidx[d] = (unsigned)a;
        sanc[d] = an;
    }
}

// ---------------------------------------------------------------------------
// K3 (validated R12 ka2 + last-block finisher): hot pass; every block writes
// its partial, fences, increments `done`; the last block re-reads all
// partials (volatile, L1-bypass) and computes the final 3 outputs in a fixed
// order (bit-deterministic regardless of which block finishes last).
// ---------------------------------------------------------------------------
__global__ __launch_bounds__(BLOCK) void k3_hot(
    const float* __restrict__ cls_,      // (B, A, 8)
    const float* __restrict__ reg_,      // (B, A, 8)
    const float* __restrict__ ann_,      // (B, M, 18)
    const float* __restrict__ sneg_,     // (B, A)
    const unsigned* __restrict__ cellBase,
    const unsigned* __restrict__ sidx,
    const float4* __restrict__ sanc,
    const float* __restrict__ bl,        // (B, NC, 128, 8)
    const unsigned* __restrict__ kl,     // (B, NC)
    float* __restrict__ partials,        // (B, NCH, 4)
    unsigned* __restrict__ done,
    float* __restrict__ out)             // 3
{
    const int slotc = blockIdx.x, b = blockIdx.y, tid = threadIdx.x;
    const int cc = slotc / CPC, chunk = slotc % CPC;
    const int base = (int)cellBase[cc];
    const int n    = (int)cellBase[cc + 1] - base;
    const int wv = tid >> 6, ln = tid & 63;

    __shared__ float s_rec[M_N][8];
    __shared__ float s_red[4][4];
    __shared__ int amLast;
    __shared__ float img[B_N][3];

    if (chunk * BLOCK >= n) {   // empty chunk: write zeros, still hit finisher
        if (tid == 0) {
            float* o = partials + ((size_t)b * NCH + slotc) * 4;
            o[0] = 0.f; o[1] = 0.f; o[2] = 0.f; o[3] = 0.f;
        }
    } else {
        const int K = (int)kl[(size_t)b * NC + cc];
        if (tid < K) {
            const float4* src = (const float4*)(bl + (((size_t)b * NC + cc) * M_N + tid) * 8);
            ((float4*)s_rec[tid])[0] = src[0];
            ((float4*)s_rec[tid])[1] = src[1];
        }

        const int i0  = chunk * BLOCK + tid;
        const bool inb = (i0 < n);
        const int gi  = base + (inb ? i0 : 0);
        const float4 an = sanc[gi];
        const int a = (int)sidx[gi];
        const float sneg_v = sneg_[(size_t)b * A_N + a];
        const float aarea = (an.z - an.x) * (an.w - an.y);
        __syncthreads();

        float m1 = -3e38f, m2 = -3e38f;
        float bn = 0.f, bs = 1.f;
        int   kb = 0;

        for (int m = 0; m < K; ++m) {     // dense: ~K=19 iterations
            const float x1 = s_rec[m][0], y1 = s_rec[m][1];
            const float x2 = s_rec[m][2], y2 = s_rec[m][3];
            const float nb = s_rec[m][4];
            const float iw = fminf(an.z, x2) - fmaxf(an.x, x1);
            const float ih = fminf(an.w, y2) - fmaxf(an.y, y1);
            const float in_ = fmaxf(iw, 0.f) * fmaxf(ih, 0.f);
            m1 = fmaxf(m1, __builtin_fmaf(3.0f, in_, nb));
            m2 = fmaxf(m2, __builtin_fmaf(3.5f, in_, nb));
            const float s = aarea - nb;               // aarea + box_area
            const bool  u2 = (in_ * bs > bn * s);     // first-wins argmax
            bn = u2 ? in_ : bn;
            bs = u2 ? s   : bs;
            kb = u2 ? m   : kb;
        }

        const bool pos = inb && (m1 >= aarea);
        const bool nonign = pos || (m2 < aarea);

        float clsS = (inb && nonign) ? sneg_v : 0.f;
        float regS = 0.f, vpS = 0.f, posC = 0.f;

        if (pos) {  // epilogue (validated math)
            posC = 1.0f;
            const int bid = (int)s_rec[kb][5];
            const float* t = ann_ + ((size_t)b * M_N + bid) * 18;
            float tt[16];
#pragma unroll
            for (int j = 0; j < 16; ++j) tt[j] = t[j];
            const int kc = (int)t[17];

            const float praw = cls_[((size_t)b * A_N + a) * 8 + kc];
            const float pkc = fminf(fmaxf(praw, 1e-4f), 1.0f - 1e-4f);
            const float negkc   = 0.75f * pkc * pkc * (-__logf(1.0f - pkc));
            const float posterm = 0.25f * (1.0f - pkc) * (1.0f - pkc) * (-__logf(pkc));
            clsS += posterm - negkc;   // bit-identical negkc cancels sneg's term

            const float aw = an.z - an.x;
            const float ah = an.w - an.y;
            const float* rp = reg_ + ((size_t)b * A_N + a) * 8;
            const float4 r0 = ((const float4*)rp)[0];
            const float4 r1 = ((const float4*)rp)[1];

            auto vp = [](float rx, float ry, float tx, float ty) {
                const float denom = sqrtf(rx * rx + ry * ry) * sqrtf(tx * tx + ty * ty);
                return 1.0f - (rx * tx + ry * ty) / fmaxf(denom, 1e-8f);
            };
            const float vp1 = vp(r0.z, r0.w,
                (tt[4] + tt[6] + tt[12] + tt[14] - (tt[0] + tt[2] + tt[8] + tt[10])) * 0.25f,
                (tt[5] + tt[7] + tt[13] + tt[15] - (tt[1] + tt[3] + tt[9] + tt[11])) * 0.25f);
            const float vp2 = vp(r1.x, r1.y,
                (tt[2] + tt[6] + tt[10] + tt[14] - (tt[0] + tt[4] + tt[8] + tt[12])) * 0.25f,
                (tt[3] + tt[7] + tt[11] + tt[15] - (tt[1] + tt[5] + tt[9] + tt[13])) * 0.25f);
            const float vp3 = vp(r1.z, r1.w,
                (tt[0] + tt[2] + tt[4] + tt[6] - (tt[8] + tt[10] + tt[12] + tt[14])) * 0.25f,
                (tt[1] + tt[3] + tt[5] + tt[7] - (tt[9] + tt[11] + tt[13] + tt[15])) * 0.25f);
            vpS = (vp1 + vp2 + vp3) * (1.0f / 3.0f);

            const float s2v[8] = {-1, -1, 1, 1, -1, -1, 1, 1};
            const float s4v[8] = {-1, 1, -1, 1, -1, 1, -1, 1};
            const float s6v[8] = {1, 1, 1, 1, -1, -1, -1, -1};
            const float acx2 = an.x + 0.5f * aw;
            const float acy2 = an.y + 0.5f * ah;
            float ssum = 0.f;
#pragma unroll
            for (int j = 0; j < 8; ++j) {
                const float px = r0.x + r0.z * s2v[j] + r1.x * s4v[j] + r1.z * s6v[j];
                const float py = r0.y + r0.w * s2v[j] + r1.y * s4v[j] + r1.w * s6v[j];
                const float tx = (tt[2 * j]     - acx2) / aw;
                const float ty = (tt[2 * j + 1] - acy2) / ah;
                const float dx = fabsf(px - tx);
                const float dy = fabsf(py - ty);
                ssum += (dx <= (1.0f / 9.0f)) ? 4.5f * dx * dx : dx - (0.5f / 9.0f);
                ssum += (dy <= (1.0f / 9.0f)) ? 4.5f * dy * dy : dy - (0.5f / 9.0f);
            }
            regS = ssum * (1.0f / 16.0f);
        }

        // block reduction (validated tail)
#pragma unroll
        for (int off = 32; off; off >>= 1) {
            clsS += __shfl_down(clsS, off);
            regS += __shfl_down(regS, off);
            vpS  += __shfl_down(vpS, off);
            posC += __shfl_down(posC, off);
        }
        if (ln == 0) {
            s_red[wv][0] = clsS; s_red[wv][1] = regS;
            s_red[wv][2] = vpS;  s_red[wv][3] = posC;
        }
        __syncthreads();
        if (tid == 0) {
            float C = 0, R = 0, V = 0, P = 0;
            for (int w2 = 0; w2 < 4; ++w2) {
                C += s_red[w2][0]; R += s_red[w2][1];
                V += s_red[w2][2]; P += s_red[w2][3];
            }
            float* o = partials + ((size_t)b * NCH + slotc) * 4;
            o[0] = C; o[1] = R; o[2] = V; o[3] = P;
        }
    }

    // ---- last-block finisher (replaces kc launch) ---------------------
    __threadfence();
    if (tid == 0)
        amLast = (atomicAdd(done, 1u) == TOTAL4 - 1u) ? 1 : 0;
    __syncthreads();
    if (amLast) {
        __threadfence();
        volatile const float* vq = partials;   // L1-bypass reads
#pragma unroll
        for (int rep = 0; rep < 2; ++rep) {
            const int bb = wv + rep * 4;       // wave wv: images wv, wv+4
            float c = 0.f, r = 0.f, v = 0.f, p = 0.f;
            for (int s = ln; s < NCH; s += 64) {
                const size_t q = ((size_t)bb * NCH + s) * 4;
                c += vq[q + 0]; r += vq[q + 1]; v += vq[q + 2]; p += vq[q + 3];
            }
#pragma unroll
            for (int off = 32; off; off >>= 1) {
                c += __shfl_down(c, off); r += __shfl_down(r, off);
                v += __shfl_down(v, off); p += __shfl_down(p, off);
            }
            if (ln == 0) {
                const float np_ = fmaxf(p, 1.0f);
                img[bb][0] = c / np_; img[bb][1] = r / np_; img[bb][2] = v / np_;
            }
        }
        __syncthreads();
        if (tid == 0) {
            float C = 0, R = 0, V = 0;
            for (int bb = 0; bb < B_N; ++bb) {
                C += img[bb][0]; R += img[bb][1]; V += img[bb][2];
            }
            out[0] = C * 0.125f;
            out[1] = R * 0.125f;
            out[2] = V * 0.125f;
        }
    }
}

}  // namespace

extern "C" void kernel_launch(void* const* d_in, const int* in_sizes, int n_in,
                              void* d_out, int out_size, void* d_ws, size_t ws_size,
                              hipStream_t stream)
{
    const float* cls_    = (const float*)d_in[0];
    const float* reg_    = (const float*)d_in[1];
    const float* anchors = (const float*)d_in[2];
    const float* ann     = (const float*)d_in[3];
    // d_in[4] embeddings: unused by the reference.

    char* ws = (char*)d_ws;
    unsigned* hist     = (unsigned*)(ws + OFF_HIST);
    unsigned* cellBase = (unsigned*)(ws + OFF_CB);
    unsigned* sidxp    = (unsigned*)(ws + OFF_SIDX);
    float4*   sancp    = (float4*)(ws + OFF_SANC);
    float*    snegp    = (float*)(ws + OFF_SNEG);
    float*    blp      = (float*)(ws + OFF_BL);
    unsigned* klp      = (unsigned*)(ws + OFF_KL);
    float*    partials = (float*)(ws + OFF_PART);
    unsigned* donep    = (unsigned*)(ws + OFF_DONE);

    k1_prep<<<dim3(NU1), dim3(BLOCK), 0, stream>>>(
        anchors, cls_, ann, hist, snegp, blp, klp);
    k2_scan_scatter<<<dim3(NBLK_S), dim3(BLOCK), 0, stream>>>(
        anchors, hist, cellBase, sidxp, sancp, donep);
    k3_hot<<<dim3(NCH, B_N), dim3(BLOCK), 0, stream>>>(
        cls_, reg_, ann, snegp, cellBase, sidxp, sancp, blp, klp,
        partials, donep, (float*)d_out);
}

// Round 16
// 125.179 us; speedup vs baseline: 3.6578x; 3.6578x over previous
//
#include <hip/hip_runtime.h>

namespace {

constexpr int B_N = 8;
constexpr int A_N = 100000;
constexpr int M_N = 128;
constexpr int BLOCK = 256;
constexpr int NBLK_S = (A_N + BLOCK - 1) / BLOCK;  // 391
constexpr int GX = 16, GY = 9, NC = GX * GY;       // 144 cells, 120x120
constexpr float CELL = 120.0f;
constexpr float MARGIN = 128.0f;                   // max anchor half-extent
constexpr int CPC = 4;                             // chunks/cell
constexpr int NCH = NC * CPC;                      // 576 chunk-slots per image
constexpr int NU1 = NBLK_S + B_N * NC;             // 1543 K1 blocks

// workspace layout (bytes)
constexpr size_t OFF_HIST = 0;                                      // NBLK_S*NC u32
constexpr size_t OFF_CB   = OFF_HIST + (size_t)NBLK_S * NC * 4;     // (NC+1) u32
constexpr size_t OFF_SIDX = (OFF_CB + (NC + 1) * 4 + 15) & ~size_t(15);       // A_N u32
constexpr size_t OFF_SANC = (OFF_SIDX + (size_t)A_N * 4 + 15) & ~size_t(15);  // A_N float4
constexpr size_t OFF_SNEG = OFF_SANC + (size_t)A_N * 16;            // B*A_N f32
constexpr size_t OFF_BL   = OFF_SNEG + (size_t)B_N * A_N * 4;       // B*NC*128*8 f32
constexpr size_t OFF_KL   = OFF_BL + (size_t)B_N * NC * M_N * 8 * 4;  // B*NC u32
constexpr size_t OFF_PART = (OFF_KL + (size_t)B_N * NC * 4 + 15) & ~size_t(15);  // B*NCH*4 f32

__device__ __forceinline__ int cell_of(const float4& an) {
    const float acx = 0.5f * (an.x + an.z);
    const float acy = 0.5f * (an.y + an.w);
    const int cx = min(GX - 1, max(0, (int)(acx * (1.0f / CELL))));
    const int cy = min(GY - 1, max(0, (int)(acy * (1.0f / CELL))));
    return cy * GX + cx;
}

// ---------------------------------------------------------------------------
// K1 (validated R12/R15): heterogeneous blocks.
//  [0, NBLK_S):      hist + sneg (coalesced cls stream)
//  [NBLK_S, +B*NC):  per-(image,cell) dense box lists {x1,y1,x2,y2,-area,id}
// ---------------------------------------------------------------------------
__global__ __launch_bounds__(BLOCK) void k1_prep(
    const float* __restrict__ anchors_,
    const float* __restrict__ cls_,
    const float* __restrict__ ann_,
    unsigned* __restrict__ hist,     // (NBLK_S, NC)
    float* __restrict__ sneg_,       // (B_N, A_N)
    float* __restrict__ bl,          // (B_N, NC, 128, 8)
    unsigned* __restrict__ kl)       // (B_N, NC)
{
    __shared__ unsigned h[NC];
    __shared__ unsigned long long s_w[2];
    const int blk = blockIdx.x, tid = threadIdx.x;

    if (blk < NBLK_S) {
        for (int i = tid; i < NC; i += BLOCK) h[i] = 0u;
        __syncthreads();
        const int a = blk * BLOCK + tid;
        if (a < A_N) {
            const float4 an = ((const float4*)anchors_)[a];
            atomicAdd(&h[cell_of(an)], 1u);
#pragma unroll
            for (int b = 0; b < B_N; ++b) {
                const float* cp = cls_ + ((size_t)b * A_N + a) * 8;
                const float4 cA = ((const float4*)cp)[0];
                const float4 cB = ((const float4*)cp)[1];
                const float pv[8] = {cA.x, cA.y, cA.z, cA.w, cB.x, cB.y, cB.z, cB.w};
                float s = 0.f;
#pragma unroll
                for (int c = 0; c < 8; ++c) {
                    const float p = fminf(fmaxf(pv[c], 1e-4f), 1.0f - 1e-4f);
                    s += 0.75f * p * p * (-__logf(1.0f - p));
                }
                sneg_[(size_t)b * A_N + a] = s;
            }
        }
        __syncthreads();
        for (int i = tid; i < NC; i += BLOCK) hist[(size_t)blk * NC + i] = h[i];
        return;
    }

    const int bi = blk - NBLK_S;
    const int b  = bi / NC, cc = bi % NC;
    const int ccx = cc % GX, ccy = cc / GX;
    const float lox = ccx * CELL - MARGIN, hix = ccx * CELL + CELL + MARGIN;
    const float loy = ccy * CELL - MARGIN, hiy = ccy * CELL + CELL + MARGIN;
    bool ok = false;
    float minx = 0.f, miny = 0.f, maxx = 0.f, maxy = 0.f, area = 0.f;
    if (tid < M_N) {
        const float* t = ann_ + ((size_t)b * M_N + tid) * 18;
        minx = t[0]; maxx = t[0]; miny = t[1]; maxy = t[1];
#pragma unroll
        for (int j = 1; j < 8; ++j) {
            const float x = t[2 * j], y = t[2 * j + 1];
            minx = fminf(minx, x); maxx = fmaxf(maxx, x);
            miny = fminf(miny, y); maxy = fmaxf(maxy, y);
        }
        area = (maxx - minx) * (maxy - miny);
        ok = (t[17] >= 0.0f) && (minx <= hix) && (maxx >= lox) &&
             (miny <= hiy) && (maxy >= loy);
    }
    const unsigned long long bw = __ballot(ok);
    if (tid < 128 && (tid & 63) == 0) s_w[tid >> 6] = bw;
    __syncthreads();
    const unsigned p0 = (unsigned)__popcll(s_w[0]);
    if (ok) {
        const int wq = tid >> 6;  // 0 or 1
        const int r = (int)((wq ? p0 : 0u) +
            (unsigned)__popcll(s_w[wq] & ((1ull << (tid & 63)) - 1ull)));
        float* o = bl + (((size_t)b * NC + cc) * M_N + r) * 8;
        o[0] = minx; o[1] = miny; o[2] = maxx; o[3] = maxy;
        o[4] = -area; o[5] = (float)tid; o[6] = 0.f; o[7] = 0.f;
    }
    if (tid == 0)
        kl[(size_t)b * NC + cc] = p0 + (unsigned)__popcll(s_w[1]);
}

// ---------------------------------------------------------------------------
// K2 (validated R15 merge, fence-free): per block, stream ALL hist rows with
// coalesced loads + LDS integer atomics (deterministic) -> offA[c] (rows <
// blk) and offB[c] (cell totals); LDS scan -> cell bases; then the validated
// scatter body. Block 0 publishes cellBase for K3.
// ---------------------------------------------------------------------------
__global__ __launch_bounds__(BLOCK) void k2_scan_scatter(
    const float* __restrict__ anchors_,
    const unsigned* __restrict__ hist,   // (NBLK_S, NC)
    unsigned* __restrict__ cellBase,     // NC+1
    unsigned* __restrict__ sidx, float4* __restrict__ sanc)
{
    __shared__ unsigned offA[NC];   // sum of rows < blk  (== offs[c][blk])
    __shared__ unsigned offB[NC];   // sum of all rows    (== cellTot[c])
    __shared__ unsigned sscan[BLOCK];
    __shared__ unsigned scb[NC];
    __shared__ unsigned hw[4][NC];
    const int blk = blockIdx.x, tid = threadIdx.x;
    const int ln = tid & 63, wv = tid >> 6;

    for (int i = tid; i < NC; i += BLOCK) { offA[i] = 0u; offB[i] = 0u; }
    for (int i = tid; i < 4 * NC; i += BLOCK) (&hw[0][0])[i] = 0u;
    __syncthreads();

    for (int idx = tid; idx < NBLK_S * NC; idx += BLOCK) {  // coalesced
        const unsigned v = hist[idx];
        if (v) {
            const int r = idx / NC, c = idx - r * NC;
            atomicAdd(&offB[c], v);               // integer: deterministic
            if (r < blk) atomicAdd(&offA[c], v);
        }
    }
    __syncthreads();

    const unsigned v = (tid < NC) ? offB[tid] : 0u;
    sscan[tid] = v;
    __syncthreads();
    for (int off = 1; off < BLOCK; off <<= 1) {
        const unsigned x = (tid >= off) ? sscan[tid - off] : 0u;
        __syncthreads();
        sscan[tid] += x;
        __syncthreads();
    }
    if (tid < NC) scb[tid] = sscan[tid] - v;
    if (blk == 0) {
        if (tid < NC) cellBase[tid] = sscan[tid] - v;
        if (tid == NC - 1) cellBase[NC] = sscan[tid];
    }

    // scatter (validated R9 body; offs -> offA)
    const int a = blk * BLOCK + tid;
    const bool valid = (a < A_N);
    float4 an = make_float4(0.f, 0.f, 0.f, 0.f);
    int c = -1;
    if (valid) { an = ((const float4*)anchors_)[a]; c = cell_of(an); }

    int rank = 0, cnt = 0;
    for (int j = 0; j < 64; ++j) {           // deterministic intra-wave rank
        const int cj = __shfl(c, j);
        const bool same = (cj == c);
        rank += (same && (j < ln));
        cnt  += same;
    }
    if (valid && rank == 0) hw[wv][c] = (unsigned)cnt;
    __syncthreads();
    if (valid) {
        unsigned r = (unsigned)rank;
        for (int w = 0; w < wv; ++w) r += hw[w][c];
        const unsigned d = scb[c] + offA[c] + r;
        sidx[d] = (unsigned)a;
        sanc[d] = an;
    }
}

// ---------------------------------------------------------------------------
// K3 (validated R12 ka2): hot pass. Stage K dense records (2xfloat4, tid<K),
// ONE barrier, dense K~19 loop (fused band test + first-wins argmax), inline
// pos epilogue, deterministic block reduce -> partials. No fences.
// ---------------------------------------------------------------------------
__global__ __launch_bounds__(BLOCK) void k3_hot(
    const float* __restrict__ cls_,      // (B, A, 8)
    const float* __restrict__ reg_,      // (B, A, 8)
    const float* __restrict__ ann_,      // (B, M, 18)
    const float* __restrict__ sneg_,     // (B, A)
    const unsigned* __restrict__ cellBase,
    const unsigned* __restrict__ sidx,
    const float4* __restrict__ sanc,
    const float* __restrict__ bl,        // (B, NC, 128, 8)
    const unsigned* __restrict__ kl,     // (B, NC)
    float* __restrict__ partials)        // (B, NCH, 4)
{
    const int slotc = blockIdx.x, b = blockIdx.y, tid = threadIdx.x;
    const int cc = slotc / CPC, chunk = slotc % CPC;
    const int base = (int)cellBase[cc];
    const int n    = (int)cellBase[cc + 1] - base;
    const int wv = tid >> 6, ln = tid & 63;

    __shared__ float s_rec[M_N][8];
    __shared__ float s_red[4][4];

    if (chunk * BLOCK >= n) {   // block-uniform early exit (still owns a slot)
        if (tid == 0) {
            float* o = partials + ((size_t)b * NCH + slotc) * 4;
            o[0] = 0.f; o[1] = 0.f; o[2] = 0.f; o[3] = 0.f;
        }
        return;
    }

    const int K = (int)kl[(size_t)b * NC + cc];
    if (tid < K) {
        const float4* src = (const float4*)(bl + (((size_t)b * NC + cc) * M_N + tid) * 8);
        ((float4*)s_rec[tid])[0] = src[0];
        ((float4*)s_rec[tid])[1] = src[1];
    }

    const int i0  = chunk * BLOCK + tid;
    const bool inb = (i0 < n);
    const int gi  = base + (inb ? i0 : 0);
    const float4 an = sanc[gi];
    const int a = (int)sidx[gi];
    const float sneg_v = sneg_[(size_t)b * A_N + a];
    const float aarea = (an.z - an.x) * (an.w - an.y);
    __syncthreads();

    float m1 = -3e38f, m2 = -3e38f;
    float bn = 0.f, bs = 1.f;
    int   kb = 0;

    for (int m = 0; m < K; ++m) {     // dense: ~K=19 iterations
        const float x1 = s_rec[m][0], y1 = s_rec[m][1];
        const float x2 = s_rec[m][2], y2 = s_rec[m][3];
        const float nb = s_rec[m][4];
        const float iw = fminf(an.z, x2) - fmaxf(an.x, x1);
        const float ih = fminf(an.w, y2) - fmaxf(an.y, y1);
        const float in_ = fmaxf(iw, 0.f) * fmaxf(ih, 0.f);
        m1 = fmaxf(m1, __builtin_fmaf(3.0f, in_, nb));
        m2 = fmaxf(m2, __builtin_fmaf(3.5f, in_, nb));
        const float s = aarea - nb;               // aarea + box_area
        const bool  u2 = (in_ * bs > bn * s);     // first-wins argmax
        bn = u2 ? in_ : bn;
        bs = u2 ? s   : bs;
        kb = u2 ? m   : kb;
    }

    const bool pos = inb && (m1 >= aarea);
    const bool nonign = pos || (m2 < aarea);

    float clsS = (inb && nonign) ? sneg_v : 0.f;
    float regS = 0.f, vpS = 0.f, posC = 0.f;

    if (pos) {  // epilogue (validated math); small gathers, L2/L3-resident
        posC = 1.0f;
        const int bid = (int)s_rec[kb][5];
        const float* t = ann_ + ((size_t)b * M_N + bid) * 18;
        float tt[16];
#pragma unroll
        for (int j = 0; j < 16; ++j) tt[j] = t[j];
        const int kc = (int)t[17];

        const float praw = cls_[((size_t)b * A_N + a) * 8 + kc];
        const float pkc = fminf(fmaxf(praw, 1e-4f), 1.0f - 1e-4f);
        const float negkc   = 0.75f * pkc * pkc * (-__logf(1.0f - pkc));
        const float posterm = 0.25f * (1.0f - pkc) * (1.0f - pkc) * (-__logf(pkc));
        clsS += posterm - negkc;   // bit-identical negkc cancels sneg's term

        const float aw = an.z - an.x;
        const float ah = an.w - an.y;
        const float* rp = reg_ + ((size_t)b * A_N + a) * 8;
        const float4 r0 = ((const float4*)rp)[0];
        const float4 r1 = ((const float4*)rp)[1];

        auto vp = [](float rx, float ry, float tx, float ty) {
            const float denom = sqrtf(rx * rx + ry * ry) * sqrtf(tx * tx + ty * ty);
            return 1.0f - (rx * tx + ry * ty) / fmaxf(denom, 1e-8f);
        };
        const float vp1 = vp(r0.z, r0.w,
            (tt[4] + tt[6] + tt[12] + tt[14] - (tt[0] + tt[2] + tt[8] + tt[10])) * 0.25f,
            (tt[5] + tt[7] + tt[13] + tt[15] - (tt[1] + tt[3] + tt[9] + tt[11])) * 0.25f);
        const float vp2 = vp(r1.x, r1.y,
            (tt[2] + tt[6] + tt[10] + tt[14] - (tt[0] + tt[4] + tt[8] + tt[12])) * 0.25f,
            (tt[3] + tt[7] + tt[11] + tt[15] - (tt[1] + tt[5] + tt[9] + tt[13])) * 0.25f);
        const float vp3 = vp(r1.z, r1.w,
            (tt[0] + tt[2] + tt[4] + tt[6] - (tt[8] + tt[10] + tt[12] + tt[14])) * 0.25f,
            (tt[1] + tt[3] + tt[5] + tt[7] - (tt[9] + tt[11] + tt[13] + tt[15])) * 0.25f);
        vpS = (vp1 + vp2 + vp3) * (1.0f / 3.0f);

        const float s2v[8] = {-1, -1, 1, 1, -1, -1, 1, 1};
        const float s4v[8] = {-1, 1, -1, 1, -1, 1, -1, 1};
        const float s6v[8] = {1, 1, 1, 1, -1, -1, -1, -1};
        const float acx2 = an.x + 0.5f * aw;
        const float acy2 = an.y + 0.5f * ah;
        float ssum = 0.f;
#pragma unroll
        for (int j = 0; j < 8; ++j) {
            const float px = r0.x + r0.z * s2v[j] + r1.x * s4v[j] + r1.z * s6v[j];
            const float py = r0.y + r0.w * s2v[j] + r1.y * s4v[j] + r1.w * s6v[j];
            const float tx = (tt[2 * j]     - acx2) / aw;
            const float ty = (tt[2 * j + 1] - acy2) / ah;
            const float dx = fabsf(px - tx);
            const float dy = fabsf(py - ty);
            ssum += (dx <= (1.0f / 9.0f)) ? 4.5f * dx * dx : dx - (0.5f / 9.0f);
            ssum += (dy <= (1.0f / 9.0f)) ? 4.5f * dy * dy : dy - (0.5f / 9.0f);
        }
        regS = ssum * (1.0f / 16.0f);
    }

    // ---- block reduction (deterministic, validated tail) --------------
#pragma unroll
    for (int off = 32; off; off >>= 1) {
        clsS += __shfl_down(clsS, off);
        regS += __shfl_down(regS, off);
        vpS  += __shfl_down(vpS, off);
        posC += __shfl_down(posC, off);
    }
    if (ln == 0) {
        s_red[wv][0] = clsS; s_red[wv][1] = regS;
        s_red[wv][2] = vpS;  s_red[wv][3] = posC;
    }
    __syncthreads();
    if (tid == 0) {
        float C = 0, R = 0, V = 0, P = 0;
        for (int w2 = 0; w2 < 4; ++w2) {
            C += s_red[w2][0]; R += s_red[w2][1];
            V += s_red[w2][2]; P += s_red[w2][3];
        }
        float* o = partials + ((size_t)b * NCH + slotc) * 4;
        o[0] = C; o[1] = R; o[2] = V; o[3] = P;
    }
}

// ---------------------------------------------------------------------------
// KC (validated): per-image sum + num_pos normalize + batch average.
// ---------------------------------------------------------------------------
__global__ __launch_bounds__(BLOCK) void kc_final(
    const float* __restrict__ partials,
    float* __restrict__ out)
{
    const int tid = threadIdx.x;
    __shared__ float s[4][4];
    __shared__ float accum[3];
    if (tid == 0) { accum[0] = 0.f; accum[1] = 0.f; accum[2] = 0.f; }

    for (int b = 0; b < B_N; ++b) {
        float c = 0.f, r = 0.f, v = 0.f, p = 0.f;
        for (int i = tid; i < NCH; i += BLOCK) {
            const float* q = partials + ((size_t)b * NCH + i) * 4;
            c += q[0]; r += q[1]; v += q[2]; p += q[3];
        }
#pragma unroll
        for (int off = 32; off; off >>= 1) {
            c += __shfl_down(c, off); r += __shfl_down(r, off);
            v += __shfl_down(v, off); p += __shfl_down(p, off);
        }
        const int wv = tid >> 6, ln = tid & 63;
        if (ln == 0) { s[wv][0] = c; s[wv][1] = r; s[wv][2] = v; s[wv][3] = p; }
        __syncthreads();
        if (tid == 0) {
            float C = 0, R = 0, V = 0, P = 0;
            for (int w = 0; w < 4; ++w) {
                C += s[w][0]; R += s[w][1]; V += s[w][2]; P += s[w][3];
            }
            const float np_ = fmaxf(P, 1.0f);
            accum[0] += C / np_; accum[1] += R / np_; accum[2] += V / np_;
        }
        __syncthreads();
    }
    if (tid == 0) {
        out[0] = accum[0] * 0.125f;
        out[1] = accum[1] * 0.125f;
        out[2] = accum[2] * 0.125f;
    }
}

}  // namespace

extern "C" void kernel_launch(void* const* d_in, const int* in_sizes, int n_in,
                              void* d_out, int out_size, void* d_ws, size_t ws_size,
                              hipStream_t stream)
{
    const float* cls_    = (const float*)d_in[0];
    const float* reg_    = (const float*)d_in[1];
    const float* anchors = (const float*)d_in[2];
    const float* ann     = (const float*)d_in[3];
    // d_in[4] embeddings: unused by the reference.

    char* ws = (char*)d_ws;
    unsigned* hist     = (unsigned*)(ws + OFF_HIST);
    unsigned* cellBase = (unsigned*)(ws + OFF_CB);
    unsigned* sidxp    = (unsigned*)(ws + OFF_SIDX);
    float4*   sancp    = (float4*)(ws + OFF_SANC);
    float*    snegp    = (float*)(ws + OFF_SNEG);
    float*    blp      = (float*)(ws + OFF_BL);
    unsigned* klp      = (unsigned*)(ws + OFF_KL);
    float*    partials = (float*)(ws + OFF_PART);

    k1_prep<<<dim3(NU1), dim3(BLOCK), 0, stream>>>(
        anchors, cls_, ann, hist, snegp, blp, klp);
    k2_scan_scatter<<<dim3(NBLK_S), dim3(BLOCK), 0, stream>>>(
        anchors, hist, cellBase, sidxp, sancp);
    k3_hot<<<dim3(NCH, B_N), dim3(BLOCK), 0, stream>>>(
        cls_, reg_, ann, snegp, cellBase, sidxp, sancp, blp, klp, partials);
    kc_final<<<dim3(1), dim3(BLOCK), 0, stream>>>(partials, (float*)d_out);
}

// Round 17
// 63.108 us; speedup vs baseline: 7.2554x; 1.9836x over previous
//
#include <hip/hip_runtime.h>

namespace {

constexpr int B_N = 8;
constexpr int A_N = 100000;
constexpr int M_N = 128;
constexpr int BLOCK = 256;
constexpr int NBLK_S = (A_N + BLOCK - 1) / BLOCK;  // 391
constexpr int GX = 16, GY = 9, NC = GX * GY;       // 144 cells, 120x120
constexpr float CELL = 120.0f;
constexpr float MARGIN = 128.0f;                   // max anchor half-extent
constexpr int CPC = 4;                             // chunks/cell (1024 > max pop)
constexpr int NCH = NC * CPC;                      // 576 chunk-slots per image

// workspace layout (bytes)
constexpr size_t OFF_HIST = 0;                                      // NBLK_S*NC u32
constexpr size_t OFF_OFFS = OFF_HIST + (size_t)NBLK_S * NC * 4;     // NC*NBLK_S u32
constexpr size_t OFF_CT   = OFF_OFFS + (size_t)NC * NBLK_S * 4;     // NC u32
constexpr size_t OFF_CB   = OFF_CT + NC * 4;                        // (NC+1) u32
constexpr size_t OFF_SIDX = (OFF_CB + (NC + 1) * 4 + 15) & ~size_t(15);       // A_N u32
constexpr size_t OFF_SANC = (OFF_SIDX + (size_t)A_N * 4 + 15) & ~size_t(15);  // A_N float4
constexpr size_t OFF_SNEG = OFF_SANC + (size_t)A_N * 16;            // B*A_N f32
constexpr size_t OFF_BL   = OFF_SNEG + (size_t)B_N * A_N * 4;       // B*NC*128*8 f32
constexpr size_t OFF_KL   = OFF_BL + (size_t)B_N * NC * M_N * 8 * 4;  // B*NC u32
constexpr size_t OFF_PART = (OFF_KL + (size_t)B_N * NC * 4 + 15) & ~size_t(15);  // B*NCH*4 f32

__device__ __forceinline__ int cell_of(const float4& an) {
    const float acx = 0.5f * (an.x + an.z);
    const float acy = 0.5f * (an.y + an.w);
    const int cx = min(GX - 1, max(0, (int)(acx * (1.0f / CELL))));
    const int cy = min(GY - 1, max(0, (int)(acy * (1.0f / CELL))));
    return cy * GX + cx;
}

// ---------------------------------------------------------------------------
// S1KX (validated R11/R12): heterogeneous blocks.
//  [0, NBLK_S):        hist + sneg (coalesced cls stream)
//  [NBLK_S, +B*NC):    per-(image,cell) dense box lists {x1,y1,x2,y2,-area,id}
// ---------------------------------------------------------------------------
__global__ __launch_bounds__(BLOCK) void s1kx(
    const float* __restrict__ anchors_,
    const float* __restrict__ cls_,
    const float* __restrict__ ann_,
    unsigned* __restrict__ hist,     // (NBLK_S, NC)
    float* __restrict__ sneg_,       // (B_N, A_N)
    float* __restrict__ bl,          // (B_N, NC, 128, 8)
    unsigned* __restrict__ kl)       // (B_N, NC)
{
    __shared__ unsigned h[NC];
    __shared__ unsigned long long s_w[2];
    const int blk = blockIdx.x, tid = threadIdx.x;

    if (blk < NBLK_S) {
        for (int i = tid; i < NC; i += BLOCK) h[i] = 0u;
        __syncthreads();
        const int a = blk * BLOCK + tid;
        if (a < A_N) {
            const float4 an = ((const float4*)anchors_)[a];
            atomicAdd(&h[cell_of(an)], 1u);
#pragma unroll
            for (int b = 0; b < B_N; ++b) {
                const float* cp = cls_ + ((size_t)b * A_N + a) * 8;
                const float4 cA = ((const float4*)cp)[0];
                const float4 cB = ((const float4*)cp)[1];
                const float pv[8] = {cA.x, cA.y, cA.z, cA.w, cB.x, cB.y, cB.z, cB.w};
                float s = 0.f;
#pragma unroll
                for (int c = 0; c < 8; ++c) {
                    const float p = fminf(fmaxf(pv[c], 1e-4f), 1.0f - 1e-4f);
                    s += 0.75f * p * p * (-__logf(1.0f - p));
                }
                sneg_[(size_t)b * A_N + a] = s;
            }
        }
        __syncthreads();
        for (int i = tid; i < NC; i += BLOCK) hist[(size_t)blk * NC + i] = h[i];
        return;
    }

    const int bi = blk - NBLK_S;
    const int b  = bi / NC, cc = bi % NC;
    const int ccx = cc % GX, ccy = cc / GX;
    const float lox = ccx * CELL - MARGIN, hix = ccx * CELL + CELL + MARGIN;
    const float loy = ccy * CELL - MARGIN, hiy = ccy * CELL + CELL + MARGIN;
    bool ok = false;
    float minx = 0.f, miny = 0.f, maxx = 0.f, maxy = 0.f, area = 0.f;
    if (tid < M_N) {
        const float* t = ann_ + ((size_t)b * M_N + tid) * 18;
        minx = t[0]; maxx = t[0]; miny = t[1]; maxy = t[1];
#pragma unroll
        for (int j = 1; j < 8; ++j) {
            const float x = t[2 * j], y = t[2 * j + 1];
            minx = fminf(minx, x); maxx = fmaxf(maxx, x);
            miny = fminf(miny, y); maxy = fmaxf(maxy, y);
        }
        area = (maxx - minx) * (maxy - miny);
        ok = (t[17] >= 0.0f) && (minx <= hix) && (maxx >= lox) &&
             (miny <= hiy) && (maxy >= loy);
    }
    const unsigned long long bw = __ballot(ok);
    if (tid < 128 && (tid & 63) == 0) s_w[tid >> 6] = bw;
    __syncthreads();
    const unsigned p0 = (unsigned)__popcll(s_w[0]);
    if (ok) {
        const int wq = tid >> 6;  // 0 or 1
        const int r = (int)((wq ? p0 : 0u) +
            (unsigned)__popcll(s_w[wq] & ((1ull << (tid & 63)) - 1ull)));
        float* o = bl + (((size_t)b * NC + cc) * M_N + r) * 8;
        o[0] = minx; o[1] = miny; o[2] = maxx; o[3] = maxy;
        o[4] = -area; o[5] = (float)tid; o[6] = 0.f; o[7] = 0.f;
    }
    if (tid == 0)
        kl[(size_t)b * NC + cc] = p0 + (unsigned)__popcll(s_w[1]);
}

// ---------------------------------------------------------------------------
// S2a (validated R8): per-cell block-parallel scan over 391 block counts.
// ---------------------------------------------------------------------------
__global__ __launch_bounds__(BLOCK) void s2a_scan(
    const unsigned* __restrict__ hist,
    unsigned* __restrict__ offs,
    unsigned* __restrict__ cellTot)
{
    const int c = blockIdx.x, t = threadIdx.x;
    const int k0 = 2 * t, k1 = 2 * t + 1;
    const unsigned v0 = (k0 < NBLK_S) ? hist[(size_t)k0 * NC + c] : 0u;
    const unsigned v1 = (k1 < NBLK_S) ? hist[(size_t)k1 * NC + c] : 0u;
    const unsigned mysum = v0 + v1;
    __shared__ unsigned s[BLOCK];
    s[t] = mysum;
    __syncthreads();
    for (int off = 1; off < BLOCK; off <<= 1) {
        const unsigned x = (t >= off) ? s[t - off] : 0u;
        __syncthreads();
        s[t] += x;
        __syncthreads();
    }
    const unsigned excl = s[t] - mysum;
    if (k0 < NBLK_S) offs[(size_t)c * NBLK_S + k0] = excl;
    if (k1 < NBLK_S) offs[(size_t)c * NBLK_S + k1] = excl + v0;
    if (t == BLOCK - 1) cellTot[c] = s[BLOCK - 1];
}

// ---------------------------------------------------------------------------
// S3 (validated R9): scatter; local cellTot scan -> cellBase (block 0
// publishes); deterministic __shfl intra-wave rank + per-wave LDS hist.
// ---------------------------------------------------------------------------
__global__ __launch_bounds__(BLOCK) void s3_scatter(
    const float* __restrict__ anchors_,
    const unsigned* __restrict__ offs,
    const unsigned* __restrict__ cellTot,
    unsigned* __restrict__ cellBase,
    unsigned* __restrict__ sidx, float4* __restrict__ sanc)
{
    __shared__ unsigned sscan[BLOCK];
    __shared__ unsigned scb[NC];
    __shared__ unsigned hw[4][NC];
    const int tid = threadIdx.x, blk = blockIdx.x;

    const unsigned v = (tid < NC) ? cellTot[tid] : 0u;
    sscan[tid] = v;
    for (int i = tid; i < 4 * NC; i += BLOCK) (&hw[0][0])[i] = 0u;
    __syncthreads();
    for (int off = 1; off < BLOCK; off <<= 1) {
        const unsigned x = (tid >= off) ? sscan[tid - off] : 0u;
        __syncthreads();
        sscan[tid] += x;
        __syncthreads();
    }
    if (tid < NC) scb[tid] = sscan[tid] - v;
    if (blk == 0) {
        if (tid < NC) cellBase[tid] = sscan[tid] - v;
        if (tid == NC - 1) cellBase[NC] = sscan[tid];
    }

    const int a = blk * BLOCK + tid;
    const bool valid = (a < A_N);
    float4 an = make_float4(0.f, 0.f, 0.f, 0.f);
    int c = -1;
    if (valid) { an = ((const float4*)anchors_)[a]; c = cell_of(an); }
    const int ln = tid & 63, wv = tid >> 6;

    int rank = 0, cnt = 0;
    for (int j = 0; j < 64; ++j) {
        const int cj = __shfl(c, j);
        const bool same = (cj == c);
        rank += (same && (j < ln));
        cnt  += same;
    }
    if (valid && rank == 0) hw[wv][c] = (unsigned)cnt;
    __syncthreads();
    if (valid) {
        unsigned r = (unsigned)rank;
        for (int w = 0; w < wv; ++w) r += hw[w][c];
        const unsigned d = scb[c] + offs[(size_t)c * NBLK_S + blk] + r;
        sidx[d] = (unsigned)a;
        sanc[d] = an;
    }
}

// ---------------------------------------------------------------------------
// KA2 (validated R12): grid (NCH, B). Stage K dense records (2 x float4 for
// tid<K), ONE barrier, dense K~19 loop with fused band test + first-wins
// argmax, inline pos epilogue.
// ---------------------------------------------------------------------------
__global__ __launch_bounds__(BLOCK) void ka2(
    const float* __restrict__ cls_,      // (B, A, 8)
    const float* __restrict__ reg_,      // (B, A, 8)
    const float* __restrict__ ann_,      // (B, M, 18)
    const float* __restrict__ sneg_,     // (B, A)
    const unsigned* __restrict__ cellBase,
    const unsigned* __restrict__ sidx,
    const float4* __restrict__ sanc,
    const float* __restrict__ bl,        // (B, NC, 128, 8)
    const unsigned* __restrict__ kl,     // (B, NC)
    float* __restrict__ partials)        // (B, NCH, 4)
{
    const int cc = blockIdx.x / CPC, chunk = blockIdx.x % CPC;
    const int b = blockIdx.y, tid = threadIdx.x;
    const int base = (int)cellBase[cc];
    const int n    = (int)cellBase[cc + 1] - base;

    if (chunk * BLOCK >= n) {   // block-uniform early exit (still owns a slot)
        if (tid == 0) {
            float* o = partials + ((size_t)b * NCH + blockIdx.x) * 4;
            o[0] = 0.f; o[1] = 0.f; o[2] = 0.f; o[3] = 0.f;
        }
        return;
    }

    __shared__ float s_rec[M_N][8];
    __shared__ float s_red[4][4];

    const int K = (int)kl[(size_t)b * NC + cc];   // uniform scalar load
    if (tid < K) {
        const float4* src = (const float4*)(bl + (((size_t)b * NC + cc) * M_N + tid) * 8);
        ((float4*)s_rec[tid])[0] = src[0];
        ((float4*)s_rec[tid])[1] = src[1];
    }

    const int i0  = chunk * BLOCK + tid;
    const bool inb = (i0 < n);
    const int gi  = base + (inb ? i0 : 0);
    const float4 an = sanc[gi];
    const int a = (int)sidx[gi];
    const float sneg_v = sneg_[(size_t)b * A_N + a];   // 4B gather, L2-resident
    const float aarea = (an.z - an.x) * (an.w - an.y);
    __syncthreads();

    float m1 = -3e38f, m2 = -3e38f;
    float bn = 0.f, bs = 1.f;
    int   kb = 0;

    for (int m = 0; m < K; ++m) {    // dense: ~K=19 iterations
        const float x1 = s_rec[m][0], y1 = s_rec[m][1];
        const float x2 = s_rec[m][2], y2 = s_rec[m][3];
        const float nb = s_rec[m][4];
        const float iw = fminf(an.z, x2) - fmaxf(an.x, x1);
        const float ih = fminf(an.w, y2) - fmaxf(an.y, y1);
        const float in_ = fmaxf(iw, 0.f) * fmaxf(ih, 0.f);
        m1 = fmaxf(m1, __builtin_fmaf(3.0f, in_, nb));
        m2 = fmaxf(m2, __builtin_fmaf(3.5f, in_, nb));
        const float s = aarea - nb;              // aarea + box_area
        const bool  u = (in_ * bs > bn * s);     // first-wins argmax
        bn = u ? in_ : bn;
        bs = u ? s   : bs;
        kb = u ? m   : kb;
    }

    const bool pos = inb && (m1 >= aarea);
    const bool nonign = pos || (m2 < aarea);

    float clsS = (inb && nonign) ? sneg_v : 0.f;
    float regS = 0.f, vpS = 0.f, posC = 0.f;

    if (pos) {  // epilogue (validated math); small gathers, L2/L3-resident
        posC = 1.0f;
        const int bid = (int)s_rec[kb][5];
        const float* t = ann_ + ((size_t)b * M_N + bid) * 18;
        float tt[16];
#pragma unroll
        for (int j = 0; j < 16; ++j) tt[j] = t[j];
        const int kc = (int)t[17];

        const float praw = cls_[((size_t)b * A_N + a) * 8 + kc];
        const float pkc = fminf(fmaxf(praw, 1e-4f), 1.0f - 1e-4f);
        const float negkc   = 0.75f * pkc * pkc * (-__logf(1.0f - pkc));
        const float posterm = 0.25f * (1.0f - pkc) * (1.0f - pkc) * (-__logf(pkc));
        clsS += posterm - negkc;   // bit-identical negkc cancels sneg's term

        const float aw = an.z - an.x;
        const float ah = an.w - an.y;
        const float* rp = reg_ + ((size_t)b * A_N + a) * 8;
        const float4 r0 = ((const float4*)rp)[0];
        const float4 r1 = ((const float4*)rp)[1];

        auto vp = [](float rx, float ry, float tx, float ty) {
            const float denom = sqrtf(rx * rx + ry * ry) * sqrtf(tx * tx + ty * ty);
            return 1.0f - (rx * tx + ry * ty) / fmaxf(denom, 1e-8f);
        };
        const float vp1 = vp(r0.z, r0.w,
            (tt[4] + tt[6] + tt[12] + tt[14] - (tt[0] + tt[2] + tt[8] + tt[10])) * 0.25f,
            (tt[5] + tt[7] + tt[13] + tt[15] - (tt[1] + tt[3] + tt[9] + tt[11])) * 0.25f);
        const float vp2 = vp(r1.x, r1.y,
            (tt[2] + tt[6] + tt[10] + tt[14] - (tt[0] + tt[4] + tt[8] + tt[12])) * 0.25f,
            (tt[3] + tt[7] + tt[11] + tt[15] - (tt[1] + tt[5] + tt[9] + tt[13])) * 0.25f);
        const float vp3 = vp(r1.z, r1.w,
            (tt[0] + tt[2] + tt[4] + tt[6] - (tt[8] + tt[10] + tt[12] + tt[14])) * 0.25f,
            (tt[1] + tt[3] + tt[5] + tt[7] - (tt[9] + tt[11] + tt[13] + tt[15])) * 0.25f);
        vpS = (vp1 + vp2 + vp3) * (1.0f / 3.0f);

        const float s2v[8] = {-1, -1, 1, 1, -1, -1, 1, 1};
        const float s4v[8] = {-1, 1, -1, 1, -1, 1, -1, 1};
        const float s6v[8] = {1, 1, 1, 1, -1, -1, -1, -1};
        const float acx2 = an.x + 0.5f * aw;
        const float acy2 = an.y + 0.5f * ah;
        float ssum = 0.f;
#pragma unroll
        for (int j = 0; j < 8; ++j) {
            const float px = r0.x + r0.z * s2v[j] + r1.x * s4v[j] + r1.z * s6v[j];
            const float py = r0.y + r0.w * s2v[j] + r1.y * s4v[j] + r1.w * s6v[j];
            const float tx = (tt[2 * j]     - acx2) / aw;
            const float ty = (tt[2 * j + 1] - acy2) / ah;
            const float dx = fabsf(px - tx);
            const float dy = fabsf(py - ty);
            ssum += (dx <= (1.0f / 9.0f)) ? 4.5f * dx * dx : dx - (0.5f / 9.0f);
            ssum += (dy <= (1.0f / 9.0f)) ? 4.5f * dy * dy : dy - (0.5f / 9.0f);
        }
        regS = ssum * (1.0f / 16.0f);
    }

    // ---- block reduction (deterministic, validated tail) --------------
#pragma unroll
    for (int off = 32; off; off >>= 1) {
        clsS += __shfl_down(clsS, off);
        regS += __shfl_down(regS, off);
        vpS  += __shfl_down(vpS, off);
        posC += __shfl_down(posC, off);
    }
    const int wv = tid >> 6, ln = tid & 63;
    if (ln == 0) {
        s_red[wv][0] = clsS; s_red[wv][1] = regS;
        s_red[wv][2] = vpS;  s_red[wv][3] = posC;
    }
    __syncthreads();
    if (tid == 0) {
        float C = 0, R = 0, V = 0, P = 0;
        for (int w2 = 0; w2 < 4; ++w2) {
            C += s_red[w2][0]; R += s_red[w2][1];
            V += s_red[w2][2]; P += s_red[w2][3];
        }
        float* out = partials + ((size_t)b * NCH + blockIdx.x) * 4;
        out[0] = C; out[1] = R; out[2] = V; out[3] = P;
    }
}

// ---------------------------------------------------------------------------
// KC (validated): per-image sum + num_pos normalize + batch average.
// ---------------------------------------------------------------------------
__global__ __launch_bounds__(BLOCK) void kc_final(
    const float* __restrict__ partials,
    float* __restrict__ out)
{
    const int tid = threadIdx.x;
    __shared__ float s[4][4];
    __shared__ float accum[3];
    if (tid == 0) { accum[0] = 0.f; accum[1] = 0.f; accum[2] = 0.f; }

    for (int b = 0; b < B_N; ++b) {
        float c = 0.f, r = 0.f, v = 0.f, p = 0.f;
        for (int i = tid; i < NCH; i += BLOCK) {
            const float* q = partials + ((size_t)b * NCH + i) * 4;
            c += q[0]; r += q[1]; v += q[2]; p += q[3];
        }
#pragma unroll
        for (int off = 32; off; off >>= 1) {
            c += __shfl_down(c, off); r += __shfl_down(r, off);
            v += __shfl_down(v, off); p += __shfl_down(p, off);
        }
        const int wv = tid >> 6, ln = tid & 63;
        if (ln == 0) { s[wv][0] = c; s[wv][1] = r; s[wv][2] = v; s[wv][3] = p; }
        __syncthreads();
        if (tid == 0) {
            float C = 0, R = 0, V = 0, P = 0;
            for (int w = 0; w < 4; ++w) {
                C += s[w][0]; R += s[w][1]; V += s[w][2]; P += s[w][3];
            }
            const float np_ = fmaxf(P, 1.0f);
            accum[0] += C / np_; accum[1] += R / np_; accum[2] += V / np_;
        }
        __syncthreads();
    }
    if (tid == 0) {
        out[0] = accum[0] * 0.125f;
        out[1] = accum[1] * 0.125f;
        out[2] = accum[2] * 0.125f;
    }
}

}  // namespace

extern "C" void kernel_launch(void* const* d_in, const int* in_sizes, int n_in,
                              void* d_out, int out_size, void* d_ws, size_t ws_size,
                              hipStream_t stream)
{
    const float* cls_    = (const float*)d_in[0];
    const float* reg_    = (const float*)d_in[1];
    const float* anchors = (const float*)d_in[2];
    const float* ann     = (const float*)d_in[3];
    // d_in[4] embeddings: unused by the reference.

    char* ws = (char*)d_ws;
    unsigned* hist     = (unsigned*)(ws + OFF_HIST);
    unsigned* offs     = (unsigned*)(ws + OFF_OFFS);
    unsigned* cellTot  = (unsigned*)(ws + OFF_CT);
    unsigned* cellBase = (unsigned*)(ws + OFF_CB);
    unsigned* sidxp    = (unsigned*)(ws + OFF_SIDX);
    float4*   sancp    = (float4*)(ws + OFF_SANC);
    float*    snegp    = (float*)(ws + OFF_SNEG);
    float*    blp      = (float*)(ws + OFF_BL);
    unsigned* klp      = (unsigned*)(ws + OFF_KL);
    float*    partials = (float*)(ws + OFF_PART);

    s1kx<<<dim3(NBLK_S + B_N * NC), dim3(BLOCK), 0, stream>>>(
        anchors, cls_, ann, hist, snegp, blp, klp);
    s2a_scan<<<dim3(NC), dim3(BLOCK), 0, stream>>>(hist, offs, cellTot);
    s3_scatter<<<dim3(NBLK_S), dim3(BLOCK), 0, stream>>>(anchors, offs, cellTot,
                                                         cellBase, sidxp, sancp);
    ka2<<<dim3(NCH, B_N), dim3(BLOCK), 0, stream>>>(
        cls_, reg_, ann, snegp, cellBase, sidxp, sancp, blp, klp, partials);
    kc_final<<<dim3(1), dim3(BLOCK), 0, stream>>>(partials, (float*)d_out);
}